// Round 4
// baseline (644.506 us; speedup 1.0000x reference)
//
#include <hip/hip_runtime.h>
#include <hip/hip_bf16.h>
#include <cstdint>

// MoE SwiGLU: E=8 experts, top-2, D=1024, H=2048, T=4096 tokens.
// Sparse bf16 MFMA. Round 4: wide per-wave tiles (64x64 per weight), simple
// 2-barrier loop (empirically best), single 48KB/32KB LDS buffer, 2-3 blocks/CU,
// XCD-chunked tile remap for gather L2 reuse.

#define E_ 8
#define D_ 1024
#define H_ 2048
#define T_ 4096

typedef __attribute__((ext_vector_type(8))) __bf16 bf16x8;
typedef __attribute__((ext_vector_type(4))) float f32x4;
typedef unsigned short u16;
typedef __attribute__((ext_vector_type(4))) u16 u16x4;

__device__ __forceinline__ u16 f2b(float f) {
    union { float f; unsigned int u; } v; v.f = f;
    unsigned int u = v.u;
    return (u16)((u + 0x7FFFu + ((u >> 16) & 1u)) >> 16);  // RNE
}

__device__ __forceinline__ void gld16(const void* g, void* l) {
    __builtin_amdgcn_global_load_lds((const __attribute__((address_space(1))) void*)g,
                                     (__attribute__((address_space(3))) void*)l, 16, 0, 0);
}

// ---- gate: logits, top-2, softmax, token lists; also writes xb (bf16 x) ----
__global__ void k_gate(const float* __restrict__ x, const float* __restrict__ gw,
                       int* __restrict__ cnt, int* __restrict__ tok,
                       float* __restrict__ wgt, u16* __restrict__ xb) {
    int wid = threadIdx.x >> 6, lane = threadIdx.x & 63;
    int t = blockIdx.x * 4 + wid;
    float part[E_];
#pragma unroll
    for (int e = 0; e < E_; ++e) part[e] = 0.f;
    const float* xr = x + (size_t)t * D_;
    for (int i = 0; i < D_ / 64; ++i) {
        float xv = xr[i * 64 + lane];
        xb[(size_t)t * D_ + i * 64 + lane] = f2b(xv);
#pragma unroll
        for (int e = 0; e < E_; ++e) part[e] += xv * gw[e * D_ + i * 64 + lane];
    }
#pragma unroll
    for (int off = 32; off >= 1; off >>= 1) {
#pragma unroll
        for (int e = 0; e < E_; ++e) part[e] += __shfl_xor(part[e], off);
    }
    if (lane == 0) {
        int e0 = 0; float m0 = part[0];
#pragma unroll
        for (int e = 1; e < E_; ++e) if (part[e] > m0) { m0 = part[e]; e0 = e; }
        int e1 = -1; float m1 = -3.4e38f;
#pragma unroll
        for (int e = 0; e < E_; ++e) if (e != e0 && part[e] > m1) { m1 = part[e]; e1 = e; }
        float s = __expf(m1 - m0);
        float w0 = 1.f / (1.f + s);
        float w1 = s / (1.f + s);
        int p0 = atomicAdd(&cnt[e0], 1);
        tok[e0 * T_ + p0] = t; wgt[e0 * T_ + p0] = w0;
        int p1 = atomicAdd(&cnt[e1], 1);
        tok[e1 * T_ + p1] = t; wgt[e1 * T_ + p1] = w1;
    }
}

__global__ void k_scan(const int* __restrict__ cnt, int* __restrict__ offs) {
    if (threadIdx.x == 0) {
        int a = 0;
        for (int e = 0; e < E_; ++e) { offs[e] = a; a += cnt[e]; }
    }
}

// ---- transpose W0/W1 fp32 [D][H] -> bf16 [H][D], merged launch (z: mat*8+e) ----
__global__ void k_transpose_cvt01(const float* __restrict__ W0, const float* __restrict__ W1,
                                  u16* __restrict__ w0t, u16* __restrict__ w1t) {
    __shared__ float tile[64][67];
    int z = blockIdx.z, mat = z >> 3, e = z & 7;
    const float* src = (mat ? W1 : W0) + (size_t)e * D_ * H_;
    u16* dst = (mat ? w1t : w0t) + (size_t)e * D_ * H_;
    const int R = D_, C = H_;
    int c0 = blockIdx.x * 64, r0 = blockIdx.y * 64;
    int tc4 = (threadIdx.x & 15) * 4, tr = threadIdx.x >> 4;
#pragma unroll
    for (int p = 0; p < 4; ++p) {
        float4 v = *(const float4*)(src + (size_t)(r0 + tr + 16 * p) * C + c0 + tc4);
        tile[tr + 16 * p][tc4 + 0] = v.x;
        tile[tr + 16 * p][tc4 + 1] = v.y;
        tile[tr + 16 * p][tc4 + 2] = v.z;
        tile[tr + 16 * p][tc4 + 3] = v.w;
    }
    __syncthreads();
    int r4 = (threadIdx.x & 15) * 4, tc = threadIdx.x >> 4;
#pragma unroll
    for (int p = 0; p < 4; ++p) {
        int c = tc + 16 * p;
        u16x4 o;
#pragma unroll
        for (int j = 0; j < 4; ++j) o[j] = f2b(tile[r4 + j][c]);
        *(u16x4*)(dst + (size_t)(c0 + c) * R + r0 + r4) = o;
    }
}

// ---- transpose W2 fp32 [H][D] -> bf16 [D][H] ----
__global__ void k_transpose_cvt2(const float* __restrict__ W2, u16* __restrict__ w2t) {
    __shared__ float tile[64][67];
    int e = blockIdx.z;
    const float* src = W2 + (size_t)e * H_ * D_;
    u16* dst = w2t + (size_t)e * H_ * D_;
    const int R = H_, C = D_;
    int c0 = blockIdx.x * 64, r0 = blockIdx.y * 64;
    int tc4 = (threadIdx.x & 15) * 4, tr = threadIdx.x >> 4;
#pragma unroll
    for (int p = 0; p < 4; ++p) {
        float4 v = *(const float4*)(src + (size_t)(r0 + tr + 16 * p) * C + c0 + tc4);
        tile[tr + 16 * p][tc4 + 0] = v.x;
        tile[tr + 16 * p][tc4 + 1] = v.y;
        tile[tr + 16 * p][tc4 + 2] = v.z;
        tile[tr + 16 * p][tc4 + 3] = v.w;
    }
    __syncthreads();
    int r4 = (threadIdx.x & 15) * 4, tc = threadIdx.x >> 4;
#pragma unroll
    for (int p = 0; p < 4; ++p) {
        int c = tc + 16 * p;
        u16x4 o;
#pragma unroll
        for (int j = 0; j < 4; ++j) o[j] = f2b(tile[r4 + j][c]);
        *(u16x4*)(dst + (size_t)(c0 + c) * R + r0 + r4) = o;
    }
}

// ---- GEMM1: gathered X[128,1024] @ {W0t,W1t}[128 cols] -> g = h0*silu(h1), bf16 ----
// 256 thr = 4 waves (2M x 2N); per-wave 64x64 per weight; 48KB single-buffer LDS.
__launch_bounds__(256, 2)
__global__ void k_gemm1(const u16* __restrict__ xb, const u16* __restrict__ w0t,
                        const u16* __restrict__ w1t, const float* __restrict__ b0,
                        const float* __restrict__ b1, const int* __restrict__ tok,
                        const int* __restrict__ cnt, const int* __restrict__ offs,
                        u16* __restrict__ gbuf) {
    int e = blockIdx.z;
    // XCD-chunked remap within expert slice (512 blocks = 64 per XCD)
    int bid = blockIdx.y * 16 + blockIdx.x;
    int xcd = bid & 7, lb = xcd * 64 + (bid >> 3);
    int ct = lb & 15, rt = lb >> 4;
    int cN = cnt[e];
    if (rt * 128 >= cN) return;
    __shared__ char lds[49152];  // A[128][64K] @0 (16KB) | B0[128][64K] @16K | B1 @32K
    int tid = threadIdx.x, wid = tid >> 6, lane = tid & 63;
    int wm = wid >> 1, wn = wid & 1;
    const int* tokE = tok + e * T_;
    const u16* w0e = w0t + (size_t)e * H_ * D_;
    const u16* w1e = w1t + (size_t)e * H_ * D_;

    size_t aoff[4]; int adst[4];
#pragma unroll
    for (int p = 0; p < 4; ++p) {
        int cid = p * 256 + tid, r = cid >> 3, c = cid & 7, cc = c ^ (r & 7);
        int tk = tokE[min(rt * 128 + r, cN - 1)];
        aoff[p] = (size_t)tk * D_ + cc * 8;
        adst[p] = p * 4096 + wid * 1024;
    }
    size_t boff[4]; int bdst[4];
#pragma unroll
    for (int p = 0; p < 4; ++p) {
        int cid = p * 256 + tid, n = cid >> 3, c = cid & 7, cc = c ^ (n & 7);
        boff[p] = (size_t)(ct * 128 + n) * D_ + cc * 8;
        bdst[p] = p * 4096 + wid * 1024;
    }

    f32x4 acc0[4][4], acc1[4][4];
#pragma unroll
    for (int m = 0; m < 4; ++m)
#pragma unroll
        for (int n = 0; n < 4; ++n) { acc0[m][n] = (f32x4)0.f; acc1[m][n] = (f32x4)0.f; }

    for (int kt = 0; kt < D_ / 64; ++kt) {
        int k0 = kt * 64;
        __syncthreads();
#pragma unroll
        for (int p = 0; p < 4; ++p) gld16(xb + aoff[p] + k0, lds + adst[p]);
#pragma unroll
        for (int p = 0; p < 4; ++p) gld16(w0e + boff[p] + k0, lds + 16384 + bdst[p]);
#pragma unroll
        for (int p = 0; p < 4; ++p) gld16(w1e + boff[p] + k0, lds + 32768 + bdst[p]);
        __syncthreads();
#pragma unroll
        for (int ks = 0; ks < 2; ++ks) {
            int kc = ks * 4 + (lane >> 4);
            bf16x8 af[4], b0f[4], b1f[4];
#pragma unroll
            for (int m = 0; m < 4; ++m) {
                int row = wm * 64 + m * 16 + (lane & 15);
                af[m] = *(const bf16x8*)(lds + row * 128 + ((kc ^ (row & 7)) << 4));
            }
#pragma unroll
            for (int n = 0; n < 4; ++n) {
                int nr = wn * 64 + n * 16 + (lane & 15);
                int so = nr * 128 + ((kc ^ (nr & 7)) << 4);
                b0f[n] = *(const bf16x8*)(lds + 16384 + so);
                b1f[n] = *(const bf16x8*)(lds + 32768 + so);
            }
            __builtin_amdgcn_s_setprio(1);
#pragma unroll
            for (int m = 0; m < 4; ++m)
#pragma unroll
                for (int n = 0; n < 4; ++n) {
                    acc0[m][n] = __builtin_amdgcn_mfma_f32_16x16x32_bf16(af[m], b0f[n], acc0[m][n], 0, 0, 0);
                    acc1[m][n] = __builtin_amdgcn_mfma_f32_16x16x32_bf16(af[m], b1f[n], acc1[m][n], 0, 0, 0);
                }
            __builtin_amdgcn_s_setprio(0);
        }
    }
    int off_e = offs[e];
#pragma unroll
    for (int n = 0; n < 4; ++n) {
        int hc = ct * 128 + wn * 64 + n * 16 + (lane & 15);
        float bb0 = b0[e * H_ + hc], bb1 = b1[e * H_ + hc];
#pragma unroll
        for (int m = 0; m < 4; ++m)
#pragma unroll
            for (int i = 0; i < 4; ++i) {
                int idx = rt * 128 + wm * 64 + m * 16 + (lane >> 4) * 4 + i;
                if (idx < cN) {
                    float h0 = acc0[m][n][i] + bb0;
                    float h1 = acc1[m][n][i] + bb1;
                    float g = h0 * h1 / (1.f + __expf(-h1));
                    gbuf[(size_t)(off_e + idx) * H_ + hc] = f2b(g);
                }
            }
    }
}

// ---- GEMM2: g[128,2048] @ W2t[128 cols] -> scaled atomicAdd into out ----
__launch_bounds__(256, 3)
__global__ void k_gemm2(const u16* __restrict__ gbuf, const u16* __restrict__ w2t,
                        const float* __restrict__ b2, const int* __restrict__ tok,
                        const float* __restrict__ wgt, const int* __restrict__ cnt,
                        const int* __restrict__ offs, float* __restrict__ out) {
    int e = blockIdx.z;
    // XCD-chunked remap (256 blocks = 32 per XCD)
    int bid = blockIdx.y * 8 + blockIdx.x;
    int xcd = bid & 7, lb = xcd * 32 + (bid >> 3);
    int ct = lb & 7, rt = lb >> 3;
    int cN = cnt[e];
    if (rt * 128 >= cN) return;
    __shared__ char lds[32768];  // A[128][64K] @0 | B[128][64K] @16K
    int tid = threadIdx.x, wid = tid >> 6, lane = tid & 63;
    int wm = wid >> 1, wn = wid & 1;
    int off_e = offs[e];
    const u16* Ag = gbuf + (size_t)(off_e + rt * 128) * H_;  // padded tail allows over-read
    const u16* Bw = w2t + (size_t)e * D_ * H_ + (size_t)(ct * 128) * H_;

    size_t aoff[4], boff[4]; int sdst[4];
#pragma unroll
    for (int p = 0; p < 4; ++p) {
        int cid = p * 256 + tid, r = cid >> 3, c = cid & 7, cc = c ^ (r & 7);
        aoff[p] = (size_t)r * H_ + cc * 8;
        boff[p] = (size_t)r * H_ + cc * 8;
        sdst[p] = p * 4096 + wid * 1024;
    }

    f32x4 acc[4][4];
#pragma unroll
    for (int m = 0; m < 4; ++m)
#pragma unroll
        for (int n = 0; n < 4; ++n) acc[m][n] = (f32x4)0.f;

    for (int kt = 0; kt < H_ / 64; ++kt) {
        int k0 = kt * 64;
        __syncthreads();
#pragma unroll
        for (int p = 0; p < 4; ++p) gld16(Ag + aoff[p] + k0, lds + sdst[p]);
#pragma unroll
        for (int p = 0; p < 4; ++p) gld16(Bw + boff[p] + k0, lds + 16384 + sdst[p]);
        __syncthreads();
#pragma unroll
        for (int ks = 0; ks < 2; ++ks) {
            int kc = ks * 4 + (lane >> 4);
            bf16x8 af[4], bfr[4];
#pragma unroll
            for (int m = 0; m < 4; ++m) {
                int row = wm * 64 + m * 16 + (lane & 15);
                af[m] = *(const bf16x8*)(lds + row * 128 + ((kc ^ (row & 7)) << 4));
            }
#pragma unroll
            for (int n = 0; n < 4; ++n) {
                int nr = wn * 64 + n * 16 + (lane & 15);
                bfr[n] = *(const bf16x8*)(lds + 16384 + nr * 128 + ((kc ^ (nr & 7)) << 4));
            }
            __builtin_amdgcn_s_setprio(1);
#pragma unroll
            for (int m = 0; m < 4; ++m)
#pragma unroll
                for (int n = 0; n < 4; ++n)
                    acc[m][n] = __builtin_amdgcn_mfma_f32_16x16x32_bf16(af[m], bfr[n], acc[m][n], 0, 0, 0);
            __builtin_amdgcn_s_setprio(0);
        }
    }
    const int* tokE = tok + e * T_;
    const float* wgtE = wgt + e * T_;
#pragma unroll
    for (int m = 0; m < 4; ++m)
#pragma unroll
        for (int i = 0; i < 4; ++i) {
            int idx = rt * 128 + wm * 64 + m * 16 + (lane >> 4) * 4 + i;
            if (idx < cN) {
                int tk = tokE[idx];
                float w = wgtE[idx];
#pragma unroll
                for (int n = 0; n < 4; ++n) {
                    int dc = ct * 128 + wn * 64 + n * 16 + (lane & 15);
                    float val = acc[m][n][i] + b2[e * D_ + dc];
                    atomicAdd(out + (size_t)tk * D_ + dc, w * val);
                }
            }
        }
}

extern "C" void kernel_launch(void* const* d_in, const int* in_sizes, int n_in,
                              void* d_out, int out_size, void* d_ws, size_t ws_size,
                              hipStream_t stream) {
    const float* x  = (const float*)d_in[0];
    const float* gw = (const float*)d_in[1];
    const float* W0 = (const float*)d_in[2];
    const float* b0 = (const float*)d_in[3];
    const float* W1 = (const float*)d_in[4];
    const float* b1 = (const float*)d_in[5];
    const float* W2 = (const float*)d_in[6];
    const float* b2 = (const float*)d_in[7];
    float* out = (float*)d_out;

    char* ws = (char*)d_ws;
    size_t off = 0;
    u16* xb   = (u16*)(ws + off); off += (size_t)T_ * D_ * 2;             // 8 MB
    u16* w0t  = (u16*)(ws + off); off += (size_t)E_ * H_ * D_ * 2;        // 32 MB
    u16* w1t  = (u16*)(ws + off); off += (size_t)E_ * H_ * D_ * 2;        // 32 MB
    u16* w2t  = (u16*)(ws + off); off += (size_t)E_ * D_ * H_ * 2;        // 32 MB
    u16* gbuf = (u16*)(ws + off); off += (size_t)(T_ * 2 + 256) * H_ * 2; // padded tail
    int*   tok  = (int*)(ws + off);   off += (size_t)E_ * T_ * 4;
    float* wgt  = (float*)(ws + off); off += (size_t)E_ * T_ * 4;
    int*   cnt  = (int*)(ws + off);   off += 64;
    int*   offs = (int*)(ws + off);   off += 64;

    hipMemsetAsync(d_out, 0, (size_t)out_size * 4, stream);
    if (ws_size < off) return;  // workspace too small: leave zeros (visible failure)
    hipMemsetAsync(cnt, 0, 64, stream);

    k_gate<<<T_ / 4, 256, 0, stream>>>(x, gw, cnt, tok, wgt, xb);
    k_scan<<<1, 64, 0, stream>>>(cnt, offs);
    k_transpose_cvt01<<<dim3(H_ / 64, D_ / 64, 16), 256, 0, stream>>>(W0, W1, w0t, w1t);
    k_transpose_cvt2<<<dim3(D_ / 64, H_ / 64, E_), 256, 0, stream>>>(W2, w2t);
    k_gemm1<<<dim3(16, 32, E_), 256, 0, stream>>>(xb, w0t, w1t, b0, b1, tok, cnt, offs, gbuf);
    k_gemm2<<<dim3(8, 32, E_), 256, 0, stream>>>(gbuf, w2t, b2, tok, wgt, cnt, offs, out);
}

// Round 5
// 372.272 us; speedup vs baseline: 1.7313x; 1.7313x over previous
//
#include <hip/hip_runtime.h>
#include <hip/hip_bf16.h>
#include <cstdint>

// MoE SwiGLU: E=8 experts, top-2, D=1024, H=2048, T=4096 tokens.
// Round 5: round-4 wide per-wave tiles (64x64 per weight) with the broken
// XCD remap REMOVED (it sent all live work to XCDs 0-1 via the early-exit
// interaction), merged weight-transpose kernel.

#define E_ 8
#define D_ 1024
#define H_ 2048
#define T_ 4096

typedef __attribute__((ext_vector_type(8))) __bf16 bf16x8;
typedef __attribute__((ext_vector_type(4))) float f32x4;
typedef unsigned short u16;
typedef __attribute__((ext_vector_type(4))) u16 u16x4;

__device__ __forceinline__ u16 f2b(float f) {
    union { float f; unsigned int u; } v; v.f = f;
    unsigned int u = v.u;
    return (u16)((u + 0x7FFFu + ((u >> 16) & 1u)) >> 16);  // RNE
}

__device__ __forceinline__ void gld16(const void* g, void* l) {
    __builtin_amdgcn_global_load_lds((const __attribute__((address_space(1))) void*)g,
                                     (__attribute__((address_space(3))) void*)l, 16, 0, 0);
}

// ---- gate: logits, top-2, softmax, token lists; also writes xb (bf16 x) ----
__global__ void k_gate(const float* __restrict__ x, const float* __restrict__ gw,
                       int* __restrict__ cnt, int* __restrict__ tok,
                       float* __restrict__ wgt, u16* __restrict__ xb) {
    int wid = threadIdx.x >> 6, lane = threadIdx.x & 63;
    int t = blockIdx.x * 4 + wid;
    float part[E_];
#pragma unroll
    for (int e = 0; e < E_; ++e) part[e] = 0.f;
    const float* xr = x + (size_t)t * D_;
    for (int i = 0; i < D_ / 64; ++i) {
        float xv = xr[i * 64 + lane];
        xb[(size_t)t * D_ + i * 64 + lane] = f2b(xv);
#pragma unroll
        for (int e = 0; e < E_; ++e) part[e] += xv * gw[e * D_ + i * 64 + lane];
    }
#pragma unroll
    for (int off = 32; off >= 1; off >>= 1) {
#pragma unroll
        for (int e = 0; e < E_; ++e) part[e] += __shfl_xor(part[e], off);
    }
    if (lane == 0) {
        int e0 = 0; float m0 = part[0];
#pragma unroll
        for (int e = 1; e < E_; ++e) if (part[e] > m0) { m0 = part[e]; e0 = e; }
        int e1 = -1; float m1 = -3.4e38f;
#pragma unroll
        for (int e = 0; e < E_; ++e) if (e != e0 && part[e] > m1) { m1 = part[e]; e1 = e; }
        float s = __expf(m1 - m0);
        float w0 = 1.f / (1.f + s);
        float w1 = s / (1.f + s);
        int p0 = atomicAdd(&cnt[e0], 1);
        tok[e0 * T_ + p0] = t; wgt[e0 * T_ + p0] = w0;
        int p1 = atomicAdd(&cnt[e1], 1);
        tok[e1 * T_ + p1] = t; wgt[e1 * T_ + p1] = w1;
    }
}

__global__ void k_scan(const int* __restrict__ cnt, int* __restrict__ offs) {
    if (threadIdx.x == 0) {
        int a = 0;
        for (int e = 0; e < E_; ++e) { offs[e] = a; a += cnt[e]; }
    }
}

// ---- merged transpose: fp32 [R][C] -> bf16 [C][R] for W0,W1 (R=D,C=H) and W2 (R=H,C=D) ----
// grid (32, 16, 24): z = which*8 + e
__global__ void k_transpose_all(const float* __restrict__ W0, const float* __restrict__ W1,
                                const float* __restrict__ W2, u16* __restrict__ w0t,
                                u16* __restrict__ w1t, u16* __restrict__ w2t) {
    __shared__ float tile[64][67];
    int z = blockIdx.z, which = z >> 3, e = z & 7;
    const float* src; u16* dst; int R, C, c0, r0;
    if (which == 0)      { src = W0 + (size_t)e * D_ * H_; dst = w0t + (size_t)e * D_ * H_;
                           R = D_; C = H_; c0 = blockIdx.x * 64; r0 = blockIdx.y * 64; }
    else if (which == 1) { src = W1 + (size_t)e * D_ * H_; dst = w1t + (size_t)e * D_ * H_;
                           R = D_; C = H_; c0 = blockIdx.x * 64; r0 = blockIdx.y * 64; }
    else                 { src = W2 + (size_t)e * H_ * D_; dst = w2t + (size_t)e * H_ * D_;
                           R = H_; C = D_; c0 = blockIdx.y * 64; r0 = blockIdx.x * 64; }
    int tc4 = (threadIdx.x & 15) * 4, tr = threadIdx.x >> 4;
#pragma unroll
    for (int p = 0; p < 4; ++p) {
        float4 v = *(const float4*)(src + (size_t)(r0 + tr + 16 * p) * C + c0 + tc4);
        tile[tr + 16 * p][tc4 + 0] = v.x;
        tile[tr + 16 * p][tc4 + 1] = v.y;
        tile[tr + 16 * p][tc4 + 2] = v.z;
        tile[tr + 16 * p][tc4 + 3] = v.w;
    }
    __syncthreads();
    int r4 = (threadIdx.x & 15) * 4, tc = threadIdx.x >> 4;
#pragma unroll
    for (int p = 0; p < 4; ++p) {
        int c = tc + 16 * p;
        u16x4 o;
#pragma unroll
        for (int j = 0; j < 4; ++j) o[j] = f2b(tile[r4 + j][c]);
        *(u16x4*)(dst + (size_t)(c0 + c) * R + r0 + r4) = o;
    }
}

// ---- GEMM1: gathered X[128,1024] @ {W0t,W1t}[128 cols] -> g = h0*silu(h1), bf16 ----
// 256 thr = 4 waves (2M x 2N); per-wave 64x64 per weight; 48KB single-buffer LDS.
__launch_bounds__(256, 2)
__global__ void k_gemm1(const u16* __restrict__ xb, const u16* __restrict__ w0t,
                        const u16* __restrict__ w1t, const float* __restrict__ b0,
                        const float* __restrict__ b1, const int* __restrict__ tok,
                        const int* __restrict__ cnt, const int* __restrict__ offs,
                        u16* __restrict__ gbuf) {
    int e = blockIdx.z, rt = blockIdx.y, ct = blockIdx.x;  // default mapping: x fastest
    int cN = cnt[e];
    if (rt * 128 >= cN) return;
    __shared__ char lds[49152];  // A[128][128B] @0 | B0 @16K | B1 @32K
    int tid = threadIdx.x, wid = tid >> 6, lane = tid & 63;
    int wm = wid >> 1, wn = wid & 1;
    const int* tokE = tok + e * T_;
    const u16* w0e = w0t + (size_t)e * H_ * D_;
    const u16* w1e = w1t + (size_t)e * H_ * D_;

    size_t aoff[4]; int adst[4];
#pragma unroll
    for (int p = 0; p < 4; ++p) {
        int cid = p * 256 + tid, r = cid >> 3, c = cid & 7, cc = c ^ (r & 7);
        int tk = tokE[min(rt * 128 + r, cN - 1)];
        aoff[p] = (size_t)tk * D_ + cc * 8;
        adst[p] = p * 4096 + wid * 1024;
    }
    size_t boff[4]; int bdst[4];
#pragma unroll
    for (int p = 0; p < 4; ++p) {
        int cid = p * 256 + tid, n = cid >> 3, c = cid & 7, cc = c ^ (n & 7);
        boff[p] = (size_t)(ct * 128 + n) * D_ + cc * 8;
        bdst[p] = p * 4096 + wid * 1024;
    }

    f32x4 acc0[4][4], acc1[4][4];
#pragma unroll
    for (int m = 0; m < 4; ++m)
#pragma unroll
        for (int n = 0; n < 4; ++n) { acc0[m][n] = (f32x4)0.f; acc1[m][n] = (f32x4)0.f; }

    for (int kt = 0; kt < D_ / 64; ++kt) {
        int k0 = kt * 64;
        __syncthreads();
#pragma unroll
        for (int p = 0; p < 4; ++p) gld16(xb + aoff[p] + k0, lds + adst[p]);
#pragma unroll
        for (int p = 0; p < 4; ++p) gld16(w0e + boff[p] + k0, lds + 16384 + bdst[p]);
#pragma unroll
        for (int p = 0; p < 4; ++p) gld16(w1e + boff[p] + k0, lds + 32768 + bdst[p]);
        __syncthreads();
#pragma unroll
        for (int ks = 0; ks < 2; ++ks) {
            int kc = ks * 4 + (lane >> 4);
            bf16x8 af[4], b0f[4], b1f[4];
#pragma unroll
            for (int m = 0; m < 4; ++m) {
                int row = wm * 64 + m * 16 + (lane & 15);
                af[m] = *(const bf16x8*)(lds + row * 128 + ((kc ^ (row & 7)) << 4));
            }
#pragma unroll
            for (int n = 0; n < 4; ++n) {
                int nr = wn * 64 + n * 16 + (lane & 15);
                int so = nr * 128 + ((kc ^ (nr & 7)) << 4);
                b0f[n] = *(const bf16x8*)(lds + 16384 + so);
                b1f[n] = *(const bf16x8*)(lds + 32768 + so);
            }
            __builtin_amdgcn_s_setprio(1);
#pragma unroll
            for (int m = 0; m < 4; ++m)
#pragma unroll
                for (int n = 0; n < 4; ++n) {
                    acc0[m][n] = __builtin_amdgcn_mfma_f32_16x16x32_bf16(af[m], b0f[n], acc0[m][n], 0, 0, 0);
                    acc1[m][n] = __builtin_amdgcn_mfma_f32_16x16x32_bf16(af[m], b1f[n], acc1[m][n], 0, 0, 0);
                }
            __builtin_amdgcn_s_setprio(0);
        }
    }
    int off_e = offs[e];
#pragma unroll
    for (int n = 0; n < 4; ++n) {
        int hc = ct * 128 + wn * 64 + n * 16 + (lane & 15);
        float bb0 = b0[e * H_ + hc], bb1 = b1[e * H_ + hc];
#pragma unroll
        for (int m = 0; m < 4; ++m)
#pragma unroll
            for (int i = 0; i < 4; ++i) {
                int idx = rt * 128 + wm * 64 + m * 16 + (lane >> 4) * 4 + i;
                if (idx < cN) {
                    float h0 = acc0[m][n][i] + bb0;
                    float h1 = acc1[m][n][i] + bb1;
                    float g = h0 * h1 / (1.f + __expf(-h1));
                    gbuf[(size_t)(off_e + idx) * H_ + hc] = f2b(g);
                }
            }
    }
}

// ---- GEMM2: g[128,2048] @ W2t[128 cols] -> scaled atomicAdd into out ----
__launch_bounds__(256, 2)
__global__ void k_gemm2(const u16* __restrict__ gbuf, const u16* __restrict__ w2t,
                        const float* __restrict__ b2, const int* __restrict__ tok,
                        const float* __restrict__ wgt, const int* __restrict__ cnt,
                        const int* __restrict__ offs, float* __restrict__ out) {
    int e = blockIdx.z, rt = blockIdx.y, ct = blockIdx.x;
    int cN = cnt[e];
    if (rt * 128 >= cN) return;
    __shared__ char lds[32768];  // A[128][128B] @0 | B @16K
    int tid = threadIdx.x, wid = tid >> 6, lane = tid & 63;
    int wm = wid >> 1, wn = wid & 1;
    int off_e = offs[e];
    const u16* Ag = gbuf + (size_t)(off_e + rt * 128) * H_;  // padded tail allows over-read
    const u16* Bw = w2t + (size_t)e * D_ * H_ + (size_t)(ct * 128) * H_;

    size_t soff[4]; int sdst[4];
#pragma unroll
    for (int p = 0; p < 4; ++p) {
        int cid = p * 256 + tid, r = cid >> 3, c = cid & 7, cc = c ^ (r & 7);
        soff[p] = (size_t)r * H_ + cc * 8;
        sdst[p] = p * 4096 + wid * 1024;
    }

    f32x4 acc[4][4];
#pragma unroll
    for (int m = 0; m < 4; ++m)
#pragma unroll
        for (int n = 0; n < 4; ++n) acc[m][n] = (f32x4)0.f;

    for (int kt = 0; kt < H_ / 64; ++kt) {
        int k0 = kt * 64;
        __syncthreads();
#pragma unroll
        for (int p = 0; p < 4; ++p) gld16(Ag + soff[p] + k0, lds + sdst[p]);
#pragma unroll
        for (int p = 0; p < 4; ++p) gld16(Bw + soff[p] + k0, lds + 16384 + sdst[p]);
        __syncthreads();
#pragma unroll
        for (int ks = 0; ks < 2; ++ks) {
            int kc = ks * 4 + (lane >> 4);
            bf16x8 af[4], bfr[4];
#pragma unroll
            for (int m = 0; m < 4; ++m) {
                int row = wm * 64 + m * 16 + (lane & 15);
                af[m] = *(const bf16x8*)(lds + row * 128 + ((kc ^ (row & 7)) << 4));
            }
#pragma unroll
            for (int n = 0; n < 4; ++n) {
                int nr = wn * 64 + n * 16 + (lane & 15);
                bfr[n] = *(const bf16x8*)(lds + 16384 + nr * 128 + ((kc ^ (nr & 7)) << 4));
            }
            __builtin_amdgcn_s_setprio(1);
#pragma unroll
            for (int m = 0; m < 4; ++m)
#pragma unroll
                for (int n = 0; n < 4; ++n)
                    acc[m][n] = __builtin_amdgcn_mfma_f32_16x16x32_bf16(af[m], bfr[n], acc[m][n], 0, 0, 0);
            __builtin_amdgcn_s_setprio(0);
        }
    }
    const int* tokE = tok + e * T_;
    const float* wgtE = wgt + e * T_;
#pragma unroll
    for (int m = 0; m < 4; ++m)
#pragma unroll
        for (int i = 0; i < 4; ++i) {
            int idx = rt * 128 + wm * 64 + m * 16 + (lane >> 4) * 4 + i;
            if (idx < cN) {
                int tk = tokE[idx];
                float w = wgtE[idx];
#pragma unroll
                for (int n = 0; n < 4; ++n) {
                    int dc = ct * 128 + wn * 64 + n * 16 + (lane & 15);
                    float val = acc[m][n][i] + b2[e * D_ + dc];
                    atomicAdd(out + (size_t)tk * D_ + dc, w * val);
                }
            }
        }
}

extern "C" void kernel_launch(void* const* d_in, const int* in_sizes, int n_in,
                              void* d_out, int out_size, void* d_ws, size_t ws_size,
                              hipStream_t stream) {
    const float* x  = (const float*)d_in[0];
    const float* gw = (const float*)d_in[1];
    const float* W0 = (const float*)d_in[2];
    const float* b0 = (const float*)d_in[3];
    const float* W1 = (const float*)d_in[4];
    const float* b1 = (const float*)d_in[5];
    const float* W2 = (const float*)d_in[6];
    const float* b2 = (const float*)d_in[7];
    float* out = (float*)d_out;

    char* ws = (char*)d_ws;
    size_t off = 0;
    u16* xb   = (u16*)(ws + off); off += (size_t)T_ * D_ * 2;             // 8 MB
    u16* w0t  = (u16*)(ws + off); off += (size_t)E_ * H_ * D_ * 2;        // 32 MB
    u16* w1t  = (u16*)(ws + off); off += (size_t)E_ * H_ * D_ * 2;        // 32 MB
    u16* w2t  = (u16*)(ws + off); off += (size_t)E_ * D_ * H_ * 2;        // 32 MB
    u16* gbuf = (u16*)(ws + off); off += (size_t)(T_ * 2 + 256) * H_ * 2; // padded tail
    int*   tok  = (int*)(ws + off);   off += (size_t)E_ * T_ * 4;
    float* wgt  = (float*)(ws + off); off += (size_t)E_ * T_ * 4;
    int*   cnt  = (int*)(ws + off);   off += 64;
    int*   offs = (int*)(ws + off);   off += 64;

    hipMemsetAsync(d_out, 0, (size_t)out_size * 4, stream);
    if (ws_size < off) return;  // workspace too small: leave zeros (visible failure)
    hipMemsetAsync(cnt, 0, 64, stream);

    k_gate<<<T_ / 4, 256, 0, stream>>>(x, gw, cnt, tok, wgt, xb);
    k_scan<<<1, 64, 0, stream>>>(cnt, offs);
    k_transpose_all<<<dim3(32, 16, 24), 256, 0, stream>>>(W0, W1, W2, w0t, w1t, w2t);
    k_gemm1<<<dim3(16, 32, E_), 256, 0, stream>>>(xb, w0t, w1t, b0, b1, tok, cnt, offs, gbuf);
    k_gemm2<<<dim3(8, 32, E_), 256, 0, stream>>>(gbuf, w2t, b2, tok, wgt, cnt, offs, out);
}